// Round 5
// baseline (207.945 us; speedup 1.0000x reference)
//
#include <hip/hip_runtime.h>
#include <hip/hip_cooperative_groups.h>
#include <math.h>

namespace cg = cooperative_groups;

// Problem constants
#define BB    4
#define CIN   256
#define HH    64
#define WWID  64
#define COUT  256
#define KKS   3
#define K2    9
#define PADV  1
#define HWSZ  4096
#define GROUPS 32
#define CPG   8
#define EPSV  1e-5f
#define KTOT  2304          // K2*CIN
#define ROWB  4608          // KTOT * sizeof(bf16)
#define NTOT  16384         // BB*HWSZ
#define NCHUNK 18           // KTOT/128

typedef __attribute__((ext_vector_type(8))) short bf16x8;
typedef __attribute__((ext_vector_type(4))) float f32x4;

#define GLOAD_LDS16(g, l) \
    __builtin_amdgcn_global_load_lds((const __attribute__((address_space(1))) unsigned int*)(g), \
                                     (__attribute__((address_space(3))) unsigned int*)(l), 16, 0, 0)

__device__ __forceinline__ unsigned short f2bf(float f) {
    unsigned u = __float_as_uint(f);
    u = (u + 0x7fffu + ((u >> 16) & 1u)) >> 16;   // RNE
    return (unsigned short)u;
}
__device__ __forceinline__ float bflo(unsigned q) { return __uint_as_float(q << 16); }
__device__ __forceinline__ float bfhi(unsigned q) { return __uint_as_float(q & 0xffff0000u); }
__device__ __forceinline__ float aload(const float* p) {
    return __hip_atomic_load(p, __ATOMIC_RELAXED, __HIP_MEMORY_SCOPE_AGENT);
}

// physical 16B-chunk position within a 256-B window, row-dependent swizzle:
// low 3 bits XOR row&7 (within 128-B half), bit3 XOR row-parity (bank-half swap)
__device__ __forceinline__ int physchunk(int c, int row) {
    return ((c & 7) ^ (row & 7)) | ((c & 8) ^ ((row & 1) << 3));
}

// ---------------------------------------------------------------------------
// k_pre: grid (129, 8, 4).
//  bx<128 : x NCHW -> NHWC bf16 tile transpose
//  bx==128: weight [Cout][Cin][K2] -> bf16 [cout][k2*256+cin] swizzled
//           (+ block (128,0,0) zeroes gstat)
// ---------------------------------------------------------------------------
__global__ __launch_bounds__(256)
void k_pre(const float* __restrict__ x, unsigned short* __restrict__ xh,
           const float* __restrict__ w, unsigned short* __restrict__ wtb,
           float* __restrict__ gstat) {
    int t = threadIdx.x;
    if (blockIdx.x < 128) {
        __shared__ float tile[32][33];
        int hw0 = blockIdx.x * 32;
        int c0  = blockIdx.y * 32;
        int b   = blockIdx.z;
        int tx = t & 31, ty = t >> 5;
        const float* xp = x + (size_t)b * CIN * HWSZ;
        #pragma unroll
        for (int i = 0; i < 4; i++)
            tile[ty + i * 8][tx] = xp[(c0 + ty + i * 8) * HWSZ + hw0 + tx];
        __syncthreads();
        int j = t >> 3, cq = t & 7;      // row hw0+j, 4 channels cq*4..
        union { unsigned short s[4]; uint2 d; } pk;
        #pragma unroll
        for (int k = 0; k < 4; k++) pk.s[k] = f2bf(tile[cq * 4 + k][j]);
        *(uint2*)((char*)xh + ((size_t)b * HWSZ * CIN + (size_t)(hw0 + j) * CIN + c0 + cq * 4) * 2) = pk.d;
    } else {
        if (blockIdx.y == 0 && blockIdx.z == 0 && t < BB * GROUPS * 2) gstat[t] = 0.f;
        int idx = (blockIdx.y * 4 + blockIdx.z) * 256 + t;   // [0,8192)
        int co = idx >> 5, c8 = idx & 31;
        int cin0 = c8 * 8;
        int w2 = c8 >> 4, c = c8 & 15;
        int pc = physchunk(c, co);
        for (int k2 = 0; k2 < K2; k2++) {
            union { unsigned short s[8]; uint4 q; } pk;
            #pragma unroll
            for (int j = 0; j < 8; j++)
                pk.s[j] = f2bf(w[(co * CIN + cin0 + j) * K2 + k2]);
            int phys = co * ROWB + k2 * 512 + w2 * 256 + pc * 16;
            *(uint4*)((char*)wtb + phys) = pk.q;
        }
    }
}

// ---------------------------------------------------------------------------
// k_sample: fused corner-prep + bilinear sampling + modulate -> val bf16
// val row n (k-major, parity-swizzled per 256-B window). Block = 16 pixels.
// ---------------------------------------------------------------------------
__global__ __launch_bounds__(256)
void k_sample(const unsigned short* __restrict__ xh,
              const float* __restrict__ offset, const float* __restrict__ mask,
              unsigned short* __restrict__ val) {
    __shared__ int   cidx[16 * K2 * 4];
    __shared__ float cwgt[16 * K2 * 4];
    int n0 = blockIdx.x * 16;
    int b  = n0 >> 12;
    int t  = threadIdx.x;

    if (t < 16 * K2) {                       // one (pixel, k2) per thread
        int p  = t / K2, k2 = t - p * K2;
        int hw = (n0 & 4095) + p;
        int ho = hw >> 6, wo = hw & 63;
        int ky = k2 / KKS, kx = k2 - ky * KKS;
        float dy = offset[((b * (2 * K2) + k2 * 2 + 0) * HWSZ) + hw];
        float dx = offset[((b * (2 * K2) + k2 * 2 + 1) * HWSZ) + hw];
        float m  = mask[(b * K2 + k2) * HWSZ + hw];
        float y  = (float)(ky + ho - PADV) + dy;
        float xc = (float)(kx + wo - PADV) + dx;
        float y0f = floorf(y), x0f = floorf(xc);
        float fy = y - y0f, fx = xc - x0f;
        int y0 = (int)y0f, x0 = (int)x0f;
        int   yy[2] = { y0, y0 + 1 };
        int   xx[2] = { x0, x0 + 1 };
        float wy[2] = { 1.f - fy, fy };
        float wx[2] = { 1.f - fx, fx };
        int base = t * 4;
        #pragma unroll
        for (int i = 0; i < 2; i++)
            #pragma unroll
            for (int j = 0; j < 2; j++) {
                int yi = yy[i], xi = xx[j];
                bool valid = (yi >= 0) && (yi < HH) && (xi >= 0) && (xi < WWID);
                int yc  = min(max(yi, 0), HH - 1);
                int xcc = min(max(xi, 0), WWID - 1);
                cidx[base + i * 2 + j] = yc * WWID + xcc;
                cwgt[base + i * 2 + j] = valid ? (wy[i] * wx[j] * m) : 0.f;
            }
    }
    __syncthreads();

    int c8 = t & 31, ps = t >> 5;
    const char* xb = (const char*)xh + (size_t)b * HWSZ * CIN * 2;
    int w2 = c8 >> 4, cc = c8 & 15;
    int nA = n0 + ps, nB = n0 + ps + 8;
    int pcA = physchunk(cc, nA), pcB = physchunk(cc, nB);

    #pragma unroll 2
    for (int k2 = 0; k2 < K2; k2++) {
        int cb0 = (ps * K2 + k2) * 4;
        int cb1 = ((ps + 8) * K2 + k2) * 4;
        uint4 q[2][4]; float wv[2][4];
        #pragma unroll
        for (int cor = 0; cor < 4; cor++) {
            wv[0][cor] = cwgt[cb0 + cor];
            q[0][cor]  = *(const uint4*)(xb + (size_t)cidx[cb0 + cor] * 512 + c8 * 16);
        }
        #pragma unroll
        for (int cor = 0; cor < 4; cor++) {
            wv[1][cor] = cwgt[cb1 + cor];
            q[1][cor]  = *(const uint4*)(xb + (size_t)cidx[cb1 + cor] * 512 + c8 * 16);
        }
        #pragma unroll
        for (int i = 0; i < 2; i++) {
            float a0=0,a1=0,a2=0,a3=0,a4=0,a5=0,a6=0,a7=0;
            #pragma unroll
            for (int cor = 0; cor < 4; cor++) {
                float wvv = wv[i][cor]; uint4 qq = q[i][cor];
                a0 += wvv * bflo(qq.x); a1 += wvv * bfhi(qq.x);
                a2 += wvv * bflo(qq.y); a3 += wvv * bfhi(qq.y);
                a4 += wvv * bflo(qq.z); a5 += wvv * bfhi(qq.z);
                a6 += wvv * bflo(qq.w); a7 += wvv * bfhi(qq.w);
            }
            union { unsigned short s[8]; uint4 q; } pk;
            pk.s[0]=f2bf(a0); pk.s[1]=f2bf(a1); pk.s[2]=f2bf(a2); pk.s[3]=f2bf(a3);
            pk.s[4]=f2bf(a4); pk.s[5]=f2bf(a5); pk.s[6]=f2bf(a6); pk.s[7]=f2bf(a7);
            int n  = i ? nB : nA;
            int pc = i ? pcB : pcA;
            *(uint4*)((char*)val + (size_t)n * ROWB + k2 * 512 + w2 * 256 + pc * 16) = pk.q;
        }
    }
}

// ---------------------------------------------------------------------------
// k_gemmfin (COOPERATIVE): C = wtb . val^T, 128m x 64n x 128k tiles, MFMA
// bf16 16x16x32, grid (2,256) = 512 blocks (2/CU). Fused bias + GN stats,
// grid sync, then normalize+ReLU from live accumulators.
// Post-sync gstat read: 16 threads/block -> LDS broadcast (NOT per-thread
// atomic loads — R3's 1M-op contention storm cost ~40 µs).
// ---------------------------------------------------------------------------
__global__ __launch_bounds__(256, 2)
void k_gemmfin(const unsigned short* __restrict__ wtb, const unsigned short* __restrict__ val,
               const float* __restrict__ bias, const float* __restrict__ gamma,
               const float* __restrict__ beta, float* __restrict__ out,
               float* __restrict__ gstat) {
    __shared__ unsigned short As[128 * 128];  // 32 KB
    __shared__ unsigned short Bs[64 * 128];   // 16 KB
    __shared__ float gs[16], gss[16];
    __shared__ float gmu[16], grstd[16];

    int m0 = blockIdx.x * 128, n0 = blockIdx.y * 64;
    int t = threadIdx.x, w = t >> 6, l = t & 63;
    int r16 = l & 15, half = l >> 4;
    int wm = w & 1, wn = w >> 1;

    if (t < 16) { gs[t] = 0.f; gss[t] = 0.f; }

    const char* ag[8]; unsigned short* lA[8];
    const char* bg[4]; unsigned short* lB[4];
    #pragma unroll
    for (int i = 0; i < 8; i++) {
        int o = (w * 8 + i) * 64 + l;
        ag[i] = (const char*)wtb + (size_t)(m0 + (o >> 4)) * ROWB + (o & 15) * 16;
        lA[i] = (unsigned short*)As + (w * 8 + i) * 512;
    }
    #pragma unroll
    for (int i = 0; i < 4; i++) {
        int o = (w * 4 + i) * 64 + l;
        bg[i] = (const char*)val + (size_t)(n0 + (o >> 4)) * ROWB + (o & 15) * 16;
        lB[i] = (unsigned short*)Bs + (w * 4 + i) * 512;
    }

    f32x4 acc[4][2];
    #pragma unroll
    for (int mi = 0; mi < 4; mi++)
        #pragma unroll
        for (int ni = 0; ni < 2; ni++) acc[mi][ni] = (f32x4)0.f;

    for (int kc = 0; kc < NCHUNK; kc++) {
        #pragma unroll
        for (int i = 0; i < 8; i++) { GLOAD_LDS16(ag[i], lA[i]); ag[i] += 256; }
        #pragma unroll
        for (int i = 0; i < 4; i++) { GLOAD_LDS16(bg[i], lB[i]); bg[i] += 256; }
        __syncthreads();
        #pragma unroll
        for (int ks = 0; ks < 4; ks++) {
            int ks4 = ks * 4 + half;
            int up  = physchunk(ks4, r16) * 8;   // shorts within 256-B LDS row
            bf16x8 af[4], bfv[2];
            #pragma unroll
            for (int mi = 0; mi < 4; mi++)
                af[mi] = *(const bf16x8*)&As[(wm * 64 + mi * 16 + r16) * 128 + up];
            #pragma unroll
            for (int ni = 0; ni < 2; ni++)
                bfv[ni] = *(const bf16x8*)&Bs[(wn * 32 + ni * 16 + r16) * 128 + up];
            #pragma unroll
            for (int mi = 0; mi < 4; mi++)
                #pragma unroll
                for (int ni = 0; ni < 2; ni++)
                    acc[mi][ni] = __builtin_amdgcn_mfma_f32_16x16x32_bf16(
                        af[mi], bfv[ni], acc[mi][ni], 0, 0, 0);
        }
        __syncthreads();
    }

    // add bias into accumulators + partial GN stats (C/D map: col=lane&15 (n), row=half*4+reg (m))
    int b = n0 >> 12;
    float s4[4] = {0,0,0,0}, ss4[4] = {0,0,0,0};
    #pragma unroll
    for (int mi = 0; mi < 4; mi++) {
        #pragma unroll
        for (int r = 0; r < 4; r++) {
            float bs = bias[m0 + wm * 64 + mi * 16 + half * 4 + r];
            #pragma unroll
            for (int ni = 0; ni < 2; ni++) {
                float v = acc[mi][ni][r] + bs;
                acc[mi][ni][r] = v;
                s4[mi] += v; ss4[mi] += v * v;
            }
        }
    }
    int gb = half >> 1;
    #pragma unroll
    for (int mi = 0; mi < 4; mi++) {
        atomicAdd(&gs [wm * 8 + mi * 2 + gb], s4[mi]);
        atomicAdd(&gss[wm * 8 + mi * 2 + gb], ss4[mi]);
    }
    __syncthreads();
    if (t < 16) {
        int g = blockIdx.x * 16 + t;
        atomicAdd(&gstat[((b * GROUPS) + g) * 2 + 0], gs[t]);
        atomicAdd(&gstat[((b * GROUPS) + g) * 2 + 1], gss[t]);
    }

    cg::this_grid().sync();

    // 16 threads load the 16 group stats this block needs; LDS broadcast
    const float inv = 1.f / (float)(CPG * HWSZ);
    if (t < 16) {
        int g = blockIdx.x * 16 + t;
        float s  = aload(&gstat[((b * GROUPS) + g) * 2 + 0]);
        float ss = aload(&gstat[((b * GROUPS) + g) * 2 + 1]);
        float mu  = s * inv;
        float var = ss * inv - mu * mu;
        gmu[t]   = mu;
        grstd[t] = rsqrtf(var + EPSV);
    }
    __syncthreads();

    #pragma unroll
    for (int mi = 0; mi < 4; mi++) {
        int gl = wm * 8 + mi * 2 + gb;
        float mu = gmu[gl], rstd = grstd[gl];
        #pragma unroll
        for (int r = 0; r < 4; r++) {
            int co = m0 + wm * 64 + mi * 16 + half * 4 + r;
            float ga = gamma[co] * rstd;
            float be = beta[co] - mu * ga;
            float* orow = out + ((size_t)(b * COUT + co)) * HWSZ;
            #pragma unroll
            for (int ni = 0; ni < 2; ni++) {
                int n = (n0 + wn * 32 + ni * 16 + r16) & 4095;
                orow[n] = fmaxf(acc[mi][ni][r] * ga + be, 0.f);
            }
        }
    }
}

// ---------------------------------------------------------------------------
extern "C" void kernel_launch(void* const* d_in, const int* in_sizes, int n_in,
                              void* d_out, int out_size, void* d_ws, size_t ws_size,
                              hipStream_t stream) {
    const float* x      = (const float*)d_in[0];
    const float* offset = (const float*)d_in[1];
    const float* mask   = (const float*)d_in[2];
    const float* weight = (const float*)d_in[3];
    const float* bias   = (const float*)d_in[4];
    const float* gamma  = (const float*)d_in[5];
    const float* beta   = (const float*)d_in[6];
    float* out = (float*)d_out;

    // workspace (~85 MB)
    unsigned short* xh    = (unsigned short*)d_ws;              //  4,194,304 us (8.4 MB)
    unsigned short* wtb   = xh + (size_t)4194304;               //    589,824 us
    unsigned short* val   = wtb + (size_t)589824;               // 37,748,736 us (75.5 MB)
    float*          gstat = (float*)(val + (size_t)37748736);   // 256 f

    k_pre<<<dim3(129, 8, 4), 256, 0, stream>>>(x, xh, weight, wtb, gstat);
    k_sample<<<NTOT / 16, 256, 0, stream>>>(xh, offset, mask, val);

    const unsigned short* wtb_c = wtb; const unsigned short* val_c = val;
    void* args[] = { (void*)&wtb_c, (void*)&val_c, (void*)&bias, (void*)&gamma,
                     (void*)&beta, (void*)&out, (void*)&gstat };
    hipLaunchCooperativeKernel((void*)k_gemmfin, dim3(2, 256), dim3(256),
                               args, 0, stream);
}

// Round 6
// 162.237 us; speedup vs baseline: 1.2817x; 1.2817x over previous
//
#include <hip/hip_runtime.h>
#include <math.h>

// Problem constants
#define BB    4
#define CIN   256
#define HH    64
#define WWID  64
#define COUT  256
#define KKS   3
#define K2    9
#define PADV  1
#define HWSZ  4096
#define GROUPS 32
#define CPG   8
#define EPSV  1e-5f
#define KTOT  2304          // K2*CIN
#define ROWB  4608          // KTOT * sizeof(bf16)
#define NTOT  16384         // BB*HWSZ
#define NCHUNK 18           // KTOT/128

typedef __attribute__((ext_vector_type(8))) short bf16x8;
typedef __attribute__((ext_vector_type(4))) float f32x4;

#define GLOAD_LDS16(g, l) \
    __builtin_amdgcn_global_load_lds((const __attribute__((address_space(1))) unsigned int*)(g), \
                                     (__attribute__((address_space(3))) unsigned int*)(l), 16, 0, 0)

__device__ __forceinline__ unsigned short f2bf(float f) {
    unsigned u = __float_as_uint(f);
    u = (u + 0x7fffu + ((u >> 16) & 1u)) >> 16;   // RNE
    return (unsigned short)u;
}
__device__ __forceinline__ float bflo(unsigned q) { return __uint_as_float(q << 16); }
__device__ __forceinline__ float bfhi(unsigned q) { return __uint_as_float(q & 0xffff0000u); }

// physical 16B-chunk position within a 256-B window, row-dependent swizzle:
// low 3 bits XOR row&7 (within 128-B half), bit3 XOR row-parity (bank-half swap)
__device__ __forceinline__ int physchunk(int c, int row) {
    return ((c & 7) ^ (row & 7)) | ((c & 8) ^ ((row & 1) << 3));
}

__device__ __forceinline__ void fma8(float* f, float w, uint4 q) {
    f[0] += w * bflo(q.x); f[1] += w * bfhi(q.x);
    f[2] += w * bflo(q.y); f[3] += w * bfhi(q.y);
    f[4] += w * bflo(q.z); f[5] += w * bfhi(q.z);
    f[6] += w * bflo(q.w); f[7] += w * bfhi(q.w);
}

// ---------------------------------------------------------------------------
// k_pre: grid (129, 8, 4).
//  bx<128 : x NCHW -> NHWC bf16 tile transpose
//  bx==128: weight [Cout][Cin][K2] -> bf16 [cout][k2*256+cin] swizzled
//           (+ block (128,0,0) zeroes gstat)
// ---------------------------------------------------------------------------
__global__ __launch_bounds__(256)
void k_pre(const float* __restrict__ x, unsigned short* __restrict__ xh,
           const float* __restrict__ w, unsigned short* __restrict__ wtb,
           float* __restrict__ gstat) {
    int t = threadIdx.x;
    if (blockIdx.x < 128) {
        __shared__ float tile[32][33];
        int hw0 = blockIdx.x * 32;
        int c0  = blockIdx.y * 32;
        int b   = blockIdx.z;
        int tx = t & 31, ty = t >> 5;
        const float* xp = x + (size_t)b * CIN * HWSZ;
        #pragma unroll
        for (int i = 0; i < 4; i++)
            tile[ty + i * 8][tx] = xp[(c0 + ty + i * 8) * HWSZ + hw0 + tx];
        __syncthreads();
        int j = t >> 3, cq = t & 7;      // row hw0+j, 4 channels cq*4..
        union { unsigned short s[4]; uint2 d; } pk;
        #pragma unroll
        for (int k = 0; k < 4; k++) pk.s[k] = f2bf(tile[cq * 4 + k][j]);
        *(uint2*)((char*)xh + ((size_t)b * HWSZ * CIN + (size_t)(hw0 + j) * CIN + c0 + cq * 4) * 2) = pk.d;
    } else {
        if (blockIdx.y == 0 && blockIdx.z == 0 && t < BB * GROUPS * 2) gstat[t] = 0.f;
        int idx = (blockIdx.y * 4 + blockIdx.z) * 256 + t;   // [0,8192)
        int co = idx >> 5, c8 = idx & 31;
        int cin0 = c8 * 8;
        int w2 = c8 >> 4, c = c8 & 15;
        int pc = physchunk(c, co);
        for (int k2 = 0; k2 < K2; k2++) {
            union { unsigned short s[8]; uint4 q; } pk;
            #pragma unroll
            for (int j = 0; j < 8; j++)
                pk.s[j] = f2bf(w[(co * CIN + cin0 + j) * K2 + k2]);
            int phys = co * ROWB + k2 * 512 + w2 * 256 + pc * 16;
            *(uint4*)((char*)wtb + phys) = pk.q;
        }
    }
}

// ---------------------------------------------------------------------------
// k_gemm (fused sampling): C[cout][n] = W . V^T where V rows are sampled
// ON THE FLY into Bs. Tiles 128m x 64n x 128k, MFMA bf16 16x16x32,
// grid (2,256) = 512 blocks (2/CU). Fused bias + GN partial stats.
// No val array, no k_sample kernel, no 151 MB HBM round-trip.
// ---------------------------------------------------------------------------
__global__ __launch_bounds__(256)
void k_gemm(const unsigned short* __restrict__ wtb, const unsigned short* __restrict__ xh,
            const float* __restrict__ offset, const float* __restrict__ mask,
            const float* __restrict__ bias, float* __restrict__ out,
            float* __restrict__ gstat) {
    __shared__ unsigned short As[128 * 128];  // 32 KB
    __shared__ unsigned short Bs[64 * 128];   // 16 KB
    __shared__ int   cidx[64 * K2 * 4];       // 9 KB
    __shared__ float cwgt[64 * K2 * 4];       // 9 KB
    __shared__ float gs[16], gss[16];

    int m0 = blockIdx.x * 128, n0 = blockIdx.y * 64;
    int b = n0 >> 12;
    int t = threadIdx.x, w = t >> 6, l = t & 63;
    int r16 = l & 15, half = l >> 4;
    int wm = w & 1, wn = w >> 1;

    if (t < 16) { gs[t] = 0.f; gss[t] = 0.f; }

    // ---- corner prep: 576 (px,k2) pairs -> cidx/cwgt
    for (int i = t; i < 64 * K2; i += 256) {
        int px = i / K2, k2 = i - px * K2;
        int hw = (n0 & 4095) + px;
        int ho = hw >> 6, wo = hw & 63;
        int ky = k2 / KKS, kx = k2 - ky * KKS;
        float dy = offset[((b * (2 * K2) + k2 * 2 + 0) * HWSZ) + hw];
        float dx = offset[((b * (2 * K2) + k2 * 2 + 1) * HWSZ) + hw];
        float m  = mask[(b * K2 + k2) * HWSZ + hw];
        float y  = (float)(ky + ho - PADV) + dy;
        float xc = (float)(kx + wo - PADV) + dx;
        float y0f = floorf(y), x0f = floorf(xc);
        float fy = y - y0f, fx = xc - x0f;
        int y0 = (int)y0f, x0 = (int)x0f;
        int   yy[2] = { y0, y0 + 1 };
        int   xx[2] = { x0, x0 + 1 };
        float wy[2] = { 1.f - fy, fy };
        float wx[2] = { 1.f - fx, fx };
        #pragma unroll
        for (int ii = 0; ii < 2; ii++)
            #pragma unroll
            for (int jj = 0; jj < 2; jj++) {
                int yi = yy[ii], xi = xx[jj];
                bool valid = (yi >= 0) && (yi < HH) && (xi >= 0) && (xi < WWID);
                int yc  = min(max(yi, 0), HH - 1);
                int xcc = min(max(xi, 0), WWID - 1);
                cidx[i * 4 + ii * 2 + jj] = yc * WWID + xcc;
                cwgt[i * 4 + ii * 2 + jj] = valid ? (wy[ii] * wx[jj] * m) : 0.f;
            }
    }

    // ---- A staging addresses (8 x 16B chunks/thread/k-chunk)
    const char* ag[8]; unsigned short* lA[8];
    #pragma unroll
    for (int i = 0; i < 8; i++) {
        int o = (w * 8 + i) * 64 + l;
        ag[i] = (const char*)wtb + (size_t)(m0 + (o >> 4)) * ROWB + (o & 15) * 16;
        lA[i] = (unsigned short*)As + (w * 8 + i) * 512;
    }

    // ---- sampling thread mapping: sc = 16B chunk (8 ch), 16 px per pass
    int sc  = t & 15;          // chunk within 256-B window (k-local 8-ch group)
    int tpx = t >> 4;          // 0..15, pixel within pass
    const char* xb = (const char*)xh + (size_t)b * HWSZ * CIN * 2;

    f32x4 acc[4][2];
    #pragma unroll
    for (int mi = 0; mi < 4; mi++)
        #pragma unroll
        for (int ni = 0; ni < 2; ni++) acc[mi][ni] = (f32x4)0.f;

    __syncthreads();   // cidx/cwgt + gs/gss ready

    for (int kc = 0; kc < NCHUNK; kc++) {
        // A: async global->LDS
        #pragma unroll
        for (int i = 0; i < 8; i++) { GLOAD_LDS16(ag[i], lA[i]); ag[i] += 256; }

        // B: sample 64 px x 128 ch slice (k2 = kc>>1, cin half h = kc&1)
        int k2 = kc >> 1, h = kc & 1;
        const char* xbs = xb + h * 256 + sc * 16;
        uint4 g[4][4];   // [pass][corner] — issue all 16 gathers first
        #pragma unroll
        for (int ps = 0; ps < 4; ps++) {
            int cb = ((ps * 16 + tpx) * K2 + k2) * 4;
            #pragma unroll
            for (int c = 0; c < 4; c++)
                g[ps][c] = *(const uint4*)(xbs + (size_t)cidx[cb + c] * 512);
        }
        #pragma unroll
        for (int ps = 0; ps < 4; ps++) {
            int px = ps * 16 + tpx;
            int cb = (px * K2 + k2) * 4;
            float f[8] = {0,0,0,0,0,0,0,0};
            fma8(f, cwgt[cb + 0], g[ps][0]);
            fma8(f, cwgt[cb + 1], g[ps][1]);
            fma8(f, cwgt[cb + 2], g[ps][2]);
            fma8(f, cwgt[cb + 3], g[ps][3]);
            union { unsigned short s[8]; uint4 q; } pk;
            #pragma unroll
            for (int e = 0; e < 8; e++) pk.s[e] = f2bf(f[e]);
            *(uint4*)&Bs[px * 128 + physchunk(sc, px) * 8] = pk.q;
        }
        __syncthreads();   // As staged (vmcnt) + Bs written (lgkmcnt)

        #pragma unroll
        for (int ks = 0; ks < 4; ks++) {
            int ks4 = ks * 4 + half;
            int up  = physchunk(ks4, r16) * 8;
            bf16x8 af[4], bfv[2];
            #pragma unroll
            for (int mi = 0; mi < 4; mi++)
                af[mi] = *(const bf16x8*)&As[(wm * 64 + mi * 16 + r16) * 128 + up];
            #pragma unroll
            for (int ni = 0; ni < 2; ni++)
                bfv[ni] = *(const bf16x8*)&Bs[(wn * 32 + ni * 16 + r16) * 128 + up];
            #pragma unroll
            for (int mi = 0; mi < 4; mi++)
                #pragma unroll
                for (int ni = 0; ni < 2; ni++)
                    acc[mi][ni] = __builtin_amdgcn_mfma_f32_16x16x32_bf16(
                        af[mi], bfv[ni], acc[mi][ni], 0, 0, 0);
        }
        __syncthreads();
    }

    // epilogue: bias + store + GN partial stats (C/D: col=lane&15 (n), row=half*4+reg (m))
    float s4[4] = {0,0,0,0}, ss4[4] = {0,0,0,0};
    #pragma unroll
    for (int mi = 0; mi < 4; mi++) {
        #pragma unroll
        for (int r = 0; r < 4; r++) {
            int co = m0 + wm * 64 + mi * 16 + half * 4 + r;
            float bs = bias[co];
            float* orow = out + ((size_t)(b * COUT + co)) * HWSZ;
            #pragma unroll
            for (int ni = 0; ni < 2; ni++) {
                int n = (n0 + wn * 32 + ni * 16 + r16) & 4095;
                float v = acc[mi][ni][r] + bs;
                orow[n] = v;
                s4[mi] += v; ss4[mi] += v * v;
            }
        }
    }
    int gb = half >> 1;
    #pragma unroll
    for (int mi = 0; mi < 4; mi++) {
        atomicAdd(&gs [wm * 8 + mi * 2 + gb], s4[mi]);
        atomicAdd(&gss[wm * 8 + mi * 2 + gb], ss4[mi]);
    }
    __syncthreads();
    if (t < 16) {
        int g = blockIdx.x * 16 + t;
        atomicAdd(&gstat[((b * GROUPS) + g) * 2 + 0], gs[t]);
        atomicAdd(&gstat[((b * GROUPS) + g) * 2 + 1], gss[t]);
    }
}

// ---------------------------------------------------------------------------
// finalize: normalize + affine + ReLU in place (float4)
// ---------------------------------------------------------------------------
__global__ __launch_bounds__(256)
void k_gnfinal(float* __restrict__ out, const float* __restrict__ gstat,
               const float* __restrict__ gamma, const float* __restrict__ beta) {
    int i4 = blockIdx.x * 256 + threadIdx.x;
    int e  = i4 * 4;
    int c  = (e >> 12) & 255;
    int b  = e >> 20;
    int g  = c >> 3;
    float s  = gstat[((b * GROUPS) + g) * 2 + 0];
    float ss = gstat[((b * GROUPS) + g) * 2 + 1];
    const float inv = 1.f / (float)(CPG * HWSZ);
    float mu  = s * inv;
    float var = ss * inv - mu * mu;
    float rstd = rsqrtf(var + EPSV);
    float ga = gamma[c] * rstd;
    float be = beta[c] - mu * ga;
    float4 v = ((float4*)out)[i4];
    v.x = fmaxf(v.x * ga + be, 0.f);
    v.y = fmaxf(v.y * ga + be, 0.f);
    v.z = fmaxf(v.z * ga + be, 0.f);
    v.w = fmaxf(v.w * ga + be, 0.f);
    ((float4*)out)[i4] = v;
}

// ---------------------------------------------------------------------------
extern "C" void kernel_launch(void* const* d_in, const int* in_sizes, int n_in,
                              void* d_out, int out_size, void* d_ws, size_t ws_size,
                              hipStream_t stream) {
    const float* x      = (const float*)d_in[0];
    const float* offset = (const float*)d_in[1];
    const float* mask   = (const float*)d_in[2];
    const float* weight = (const float*)d_in[3];
    const float* bias   = (const float*)d_in[4];
    const float* gamma  = (const float*)d_in[5];
    const float* beta   = (const float*)d_in[6];
    float* out = (float*)d_out;

    // workspace (~10 MB)
    unsigned short* xh    = (unsigned short*)d_ws;              // 4,194,304 us (8.4 MB)
    unsigned short* wtb   = xh + (size_t)4194304;               //   589,824 us (1.2 MB)
    float*          gstat = (float*)(wtb + (size_t)589824);     // 256 f

    k_pre<<<dim3(129, 8, 4), 256, 0, stream>>>(x, xh, weight, wtb, gstat);
    k_gemm<<<dim3(2, 256), 256, 0, stream>>>(wtb, xh, offset, mask, bias, out, gstat);
    k_gnfinal<<<(size_t)BB * COUT * HWSZ / 1024, 256, 0, stream>>>(out, gstat, gamma, beta);
}